// Round 3
// baseline (46.034 us; speedup 1.0000x reference)
//
#include <hip/hip_runtime.h>
#include <math.h>

#define T 16
#define A 8
#define H 128
#define E 32
#define G (4*H)   // 512 gate rows per LSTM

__device__ __forceinline__ float sigmoidf_(float x) {
    return 1.0f / (1.0f + __expf(-x));      // safe at both extremes
}
__device__ __forceinline__ float tanhf_(float x) {
    return 1.0f - 2.0f / (1.0f + __expf(2.0f * x));  // safe at both extremes
}

// Macro-expanded register file for the W_hh row: 32 NAMED float4s.
// (Arrays — even fully-unrolled ones — are allocas at SROA time and end up in
//  scratch: VGPR_Count=96 both prior rounds. Named values are SSA -> VGPRs.)
#define RPT8(M)  M(0) M(1) M(2) M(3) M(4) M(5) M(6) M(7)
#define RPT32(M) M(0)  M(1)  M(2)  M(3)  M(4)  M(5)  M(6)  M(7) \
                 M(8)  M(9)  M(10) M(11) M(12) M(13) M(14) M(15) \
                 M(16) M(17) M(18) M(19) M(20) M(21) M(22) M(23) \
                 M(24) M(25) M(26) M(27) M(28) M(29) M(30) M(31)

__global__ __attribute__((amdgpu_flat_work_group_size(512, 512),
                          amdgpu_waves_per_eu(2, 2)))
void ppo_ctrl_kernel(const int* __restrict__ old_actions,
                     const float* __restrict__ init_input,
                     const float* __restrict__ W_ih_a, const float* __restrict__ W_hh_a,
                     const float* __restrict__ b_ih_a, const float* __restrict__ b_hh_a,
                     const float* __restrict__ heads_W, const float* __restrict__ heads_b,
                     const float* __restrict__ W_ih_c, const float* __restrict__ W_hh_c,
                     const float* __restrict__ b_ih_c, const float* __restrict__ b_hh_c,
                     const float* __restrict__ critic_W, const float* __restrict__ critic_b,
                     const float* __restrict__ embed,
                     float* __restrict__ out)
{
    const int tid  = threadIdx.x;
    const int lane = tid & 63;
    const int wv   = tid >> 6;          // 8 waves
    const bool actor = (blockIdx.x == 0);

    const float* W_ih = actor ? W_ih_a : W_ih_c;
    const float* W_hh = actor ? W_hh_a : W_hh_c;
    const float* b_ih = actor ? b_ih_a : b_ih_c;
    const float* b_hh = actor ? b_hh_a : b_hh_c;

    __shared__ __align__(16) float x_s[T][E];     // 2 KB
    __shared__ __align__(16) float h_s[H];        // 512 B
    __shared__ float gates_s[G];                  // 2 KB
    __shared__ float accx_s[T][G];                // 32 KB: bias + W_ih@x(t)
    __shared__ float logit_s[A];

    // ---- build x sequence (T*E == 512 == blockDim) ----
    {
        int t0 = tid >> 5, e0 = tid & 31;
        float v;
        if (t0 == 0) v = init_input[e0];
        else         v = embed[((t0 - 1) * A + old_actions[t0 - 1]) * E + e0];
        x_s[t0][e0] = v;
    }
    if (tid < H) h_s[tid] = 0.0f;

    // ---- W_hh row -> 32 named float4 registers ----
    const float* Whh_row = W_hh + tid * H;
#define DECLW(i) float4 w##i = *(const float4*)(Whh_row + 4*(i));
    RPT32(DECLW)
#undef DECLW

    // ---- W_ih row -> 8 named float4 registers (die after prologue) ----
    const float* Wih_row = W_ih + tid * E;
#define DECLI(i) float4 wi##i = *(const float4*)(Wih_row + 4*(i));
    RPT8(DECLI)
#undef DECLI

    const float bias = b_ih[tid] + b_hh[tid];

    // critic head weights (t-invariant)
    float cw0 = 0.f, cw1 = 0.f, cb = 0.f;
    if (!actor && wv == 0) {
        cw0 = critic_W[lane];
        cw1 = critic_W[64 + lane];
        cb  = critic_b[0];
    }

    float c_reg = 0.0f;   // cell state (threads 0..127)

    __syncthreads();

    // ---- one-time: accx_s[t][row] = bias + W_ih[row,:] @ x(t) ----
    for (int t = 0; t < T; ++t) {
        float s0 = 0.f, s1 = 0.f, s2 = 0.f, s3 = 0.f;
#define MACI(i) { float4 xv = *(const float4*)(&x_s[t][4*(i)]);          \
        s0 = fmaf(wi##i.x, xv.x, s0); s1 = fmaf(wi##i.y, xv.y, s1);      \
        s2 = fmaf(wi##i.z, xv.z, s2); s3 = fmaf(wi##i.w, xv.w, s3); }
        RPT8(MACI)
#undef MACI
        accx_s[t][tid] = bias + ((s0 + s1) + (s2 + s3));  // same-thread r/w: no barrier
    }

    // ---- 16 sequential steps; critical path = W_hh @ h (128 reg-FMAs) ----
    for (int t = 0; t < T; ++t) {
        // prefetch this step's actor head weights (independent of h)
        float hw0 = 0.f, hw1 = 0.f, hb = 0.f;
        if (actor) {
            const float* hw = heads_W + (t * A + wv) * H;
            hw0 = hw[lane];
            hw1 = hw[64 + lane];
            hb  = heads_b[t * A + wv];
        }

        float a0 = 0.f, a1 = 0.f, a2 = 0.f, a3 = 0.f;
#define MACW(i) { float4 hv = *(const float4*)(&h_s[4*(i)]);             \
        a0 = fmaf(w##i.x, hv.x, a0); a1 = fmaf(w##i.y, hv.y, a1);        \
        a2 = fmaf(w##i.z, hv.z, a2); a3 = fmaf(w##i.w, hv.w, a3); }
        RPT32(MACW)
#undef MACW
        gates_s[tid] = accx_s[t][tid] + ((a0 + a1) + (a2 + a3));
        __syncthreads();

        // ---- cell/hidden update (gate order i,f,g,o) ----
        if (tid < H) {
            float gi = gates_s[tid];
            float gf = gates_s[tid + H];
            float gg = gates_s[tid + 2*H];
            float go = gates_s[tid + 3*H];
            float cn = sigmoidf_(gf) * c_reg + sigmoidf_(gi) * tanhf_(gg);
            c_reg = cn;
            h_s[tid] = sigmoidf_(go) * tanhf_(cn);
        }
        __syncthreads();

        // ---- heads ----
        if (actor) {
            float p = hw0 * h_s[lane] + hw1 * h_s[64 + lane];
            #pragma unroll
            for (int off = 32; off > 0; off >>= 1) p += __shfl_down(p, off);
            if (lane == 0) logit_s[wv] = p + hb;
        } else if (wv == 0) {
            float p = cw0 * h_s[lane] + cw1 * h_s[64 + lane];
            #pragma unroll
            for (int off = 32; off > 0; off >>= 1) p += __shfl_down(p, off);
            if (lane == 0) out[2 * T + t] = p + cb;   // values
        }
        __syncthreads();

        // softmax on one thread (8 elems) overlaps other waves' next matvec
        if (actor && tid == 0) {
            float m = logit_s[0];
            #pragma unroll
            for (int a = 1; a < A; ++a) m = fmaxf(m, logit_s[a]);
            float s = 0.f;
            #pragma unroll
            for (int a = 0; a < A; ++a) s += __expf(logit_s[a] - m);
            float logZ = m + __logf(s);
            int act = old_actions[t];
            out[t] = logit_s[act] - logZ;             // log_probs
            float ent = 0.f;
            #pragma unroll
            for (int a = 0; a < A; ++a) {
                float lp = logit_s[a] - logZ;
                ent -= __expf(lp) * lp;
            }
            out[T + t] = ent;                         // entropies
        }
    }
}

extern "C" void kernel_launch(void* const* d_in, const int* in_sizes, int n_in,
                              void* d_out, int out_size, void* d_ws, size_t ws_size,
                              hipStream_t stream) {
    const int*   old_actions = (const int*)  d_in[0];
    const float* init_input  = (const float*)d_in[1];
    const float* W_ih_a      = (const float*)d_in[2];
    const float* W_hh_a      = (const float*)d_in[3];
    const float* b_ih_a      = (const float*)d_in[4];
    const float* b_hh_a      = (const float*)d_in[5];
    const float* heads_W     = (const float*)d_in[6];
    const float* heads_b     = (const float*)d_in[7];
    const float* W_ih_c      = (const float*)d_in[8];
    const float* W_hh_c      = (const float*)d_in[9];
    const float* b_ih_c      = (const float*)d_in[10];
    const float* b_hh_c      = (const float*)d_in[11];
    const float* critic_W    = (const float*)d_in[12];
    const float* critic_b    = (const float*)d_in[13];
    const float* embed       = (const float*)d_in[14];
    float* out = (float*)d_out;

    ppo_ctrl_kernel<<<dim3(2), dim3(512), 0, stream>>>(
        old_actions, init_input,
        W_ih_a, W_hh_a, b_ih_a, b_hh_a,
        heads_W, heads_b,
        W_ih_c, W_hh_c, b_ih_c, b_hh_c,
        critic_W, critic_b, embed, out);
}

// Round 4
// 45.479 us; speedup vs baseline: 1.0122x; 1.0122x over previous
//
#include <hip/hip_runtime.h>
#include <math.h>

#define T 16
#define A 8
#define H 128
#define E 32
#define G (4*H)   // 512 gate rows per LSTM

__device__ __forceinline__ float sigmoidf_(float x) {
    return 1.0f / (1.0f + __expf(-x));      // safe at both extremes
}
__device__ __forceinline__ float tanhf_(float x) {
    return 1.0f - 2.0f / (1.0f + __expf(2.0f * x));  // safe at both extremes
}

#define RPT8(M)  M(0) M(1) M(2) M(3) M(4) M(5) M(6) M(7)
#define RPT32(M) M(0)  M(1)  M(2)  M(3)  M(4)  M(5)  M(6)  M(7) \
                 M(8)  M(9)  M(10) M(11) M(12) M(13) M(14) M(15) \
                 M(16) M(17) M(18) M(19) M(20) M(21) M(22) M(23) \
                 M(24) M(25) M(26) M(27) M(28) M(29) M(30) M(31)

// Opaque-ify a float4: asm results are NOT rematerializable, so the register
// allocator must keep them live in VGPRs across the step loop. (Without this,
// the invariant global loads get sunk back into every iteration: VGPR=112,
// 256 KB/step/CU re-read from L2 at ~135 GB/s per-CU => the observed 2.7us/step.)
#define KEEP4(v) asm volatile("" : "+v"(v.x), "+v"(v.y), "+v"(v.z), "+v"(v.w));

__global__ __attribute__((amdgpu_flat_work_group_size(512, 512),
                          amdgpu_waves_per_eu(2, 2)))
void ppo_ctrl_kernel(const int* __restrict__ old_actions,
                     const float* __restrict__ init_input,
                     const float* __restrict__ W_ih_a, const float* __restrict__ W_hh_a,
                     const float* __restrict__ b_ih_a, const float* __restrict__ b_hh_a,
                     const float* __restrict__ heads_W, const float* __restrict__ heads_b,
                     const float* __restrict__ W_ih_c, const float* __restrict__ W_hh_c,
                     const float* __restrict__ b_ih_c, const float* __restrict__ b_hh_c,
                     const float* __restrict__ critic_W, const float* __restrict__ critic_b,
                     const float* __restrict__ embed,
                     float* __restrict__ out)
{
    const int tid  = threadIdx.x;
    const int lane = tid & 63;
    const int wv   = tid >> 6;          // 8 waves
    const bool actor = (blockIdx.x == 0);

    const float* W_ih = actor ? W_ih_a : W_ih_c;
    const float* W_hh = actor ? W_hh_a : W_hh_c;
    const float* b_ih = actor ? b_ih_a : b_ih_c;
    const float* b_hh = actor ? b_hh_a : b_hh_c;

    __shared__ __align__(16) float x_s[T][E];     // 2 KB
    __shared__ __align__(16) float h_s[H];        // 512 B
    __shared__ float gates_s[G];                  // 2 KB
    __shared__ float accx_s[T][G];                // 32 KB: bias + W_ih@x(t)
    __shared__ float logit_s[A];

    // ---- build x sequence (T*E == 512 == blockDim) ----
    {
        int t0 = tid >> 5, e0 = tid & 31;
        float v;
        if (t0 == 0) v = init_input[e0];
        else         v = embed[((t0 - 1) * A + old_actions[t0 - 1]) * E + e0];
        x_s[t0][e0] = v;
    }
    if (tid < H) h_s[tid] = 0.0f;

    // ---- W_hh row -> 32 named float4s, pinned in VGPRs via opaque asm ----
    const float* Whh_row = W_hh + tid * H;
#define DECLW(i) float4 w##i = *(const float4*)(Whh_row + 4*(i)); KEEP4(w##i)
    RPT32(DECLW)
#undef DECLW

    // ---- W_ih row -> 8 named float4s (die after the prologue) ----
    const float* Wih_row = W_ih + tid * E;
#define DECLI(i) float4 wi##i = *(const float4*)(Wih_row + 4*(i));
    RPT8(DECLI)
#undef DECLI

    const float bias = b_ih[tid] + b_hh[tid];

    // critic head weights (t-invariant)
    float cw0 = 0.f, cw1 = 0.f, cb = 0.f;
    if (!actor && wv == 0) {
        cw0 = critic_W[lane];
        cw1 = critic_W[64 + lane];
        cb  = critic_b[0];
    }

    float c_reg = 0.0f;   // cell state (threads 0..127)

    __syncthreads();

    // ---- one-time: accx_s[t][row] = bias + W_ih[row,:] @ x(t) ----
    #pragma unroll 1
    for (int t = 0; t < T; ++t) {
        float s0 = 0.f, s1 = 0.f, s2 = 0.f, s3 = 0.f;
#define MACI(i) { float4 xv = *(const float4*)(&x_s[t][4*(i)]);          \
        s0 = fmaf(wi##i.x, xv.x, s0); s1 = fmaf(wi##i.y, xv.y, s1);      \
        s2 = fmaf(wi##i.z, xv.z, s2); s3 = fmaf(wi##i.w, xv.w, s3); }
        RPT8(MACI)
#undef MACI
        accx_s[t][tid] = bias + ((s0 + s1) + (s2 + s3));  // same-thread r/w: no barrier
    }

    // ---- 16 sequential steps; critical path = W_hh @ h (128 reg-FMAs) ----
    #pragma unroll 1
    for (int t = 0; t < T; ++t) {
        // prefetch this step's actor head weights (independent of h)
        float hw0 = 0.f, hw1 = 0.f, hb = 0.f;
        if (actor) {
            const float* hw = heads_W + (t * A + wv) * H;
            hw0 = hw[lane];
            hw1 = hw[64 + lane];
            hb  = heads_b[t * A + wv];
        }

        float a0 = 0.f, a1 = 0.f, a2 = 0.f, a3 = 0.f;
#define MACW(i) { float4 hv = *(const float4*)(&h_s[4*(i)]);             \
        a0 = fmaf(w##i.x, hv.x, a0); a1 = fmaf(w##i.y, hv.y, a1);        \
        a2 = fmaf(w##i.z, hv.z, a2); a3 = fmaf(w##i.w, hv.w, a3); }
        RPT32(MACW)
#undef MACW
        gates_s[tid] = accx_s[t][tid] + ((a0 + a1) + (a2 + a3));
        __syncthreads();

        // ---- cell/hidden update (gate order i,f,g,o) ----
        if (tid < H) {
            float gi = gates_s[tid];
            float gf = gates_s[tid + H];
            float gg = gates_s[tid + 2*H];
            float go = gates_s[tid + 3*H];
            float cn = sigmoidf_(gf) * c_reg + sigmoidf_(gi) * tanhf_(gg);
            c_reg = cn;
            h_s[tid] = sigmoidf_(go) * tanhf_(cn);
        }
        __syncthreads();

        // ---- heads ----
        if (actor) {
            float p = hw0 * h_s[lane] + hw1 * h_s[64 + lane];
            #pragma unroll
            for (int off = 32; off > 0; off >>= 1) p += __shfl_down(p, off);
            if (lane == 0) logit_s[wv] = p + hb;
        } else if (wv == 0) {
            float p = cw0 * h_s[lane] + cw1 * h_s[64 + lane];
            #pragma unroll
            for (int off = 32; off > 0; off >>= 1) p += __shfl_down(p, off);
            if (lane == 0) out[2 * T + t] = p + cb;   // values
        }
        __syncthreads();

        // softmax on one thread (8 elems) overlaps other waves' next matvec
        if (actor && tid == 0) {
            float m = logit_s[0];
            #pragma unroll
            for (int a = 1; a < A; ++a) m = fmaxf(m, logit_s[a]);
            float s = 0.f;
            #pragma unroll
            for (int a = 0; a < A; ++a) s += __expf(logit_s[a] - m);
            float logZ = m + __logf(s);
            int act = old_actions[t];
            out[t] = logit_s[act] - logZ;             // log_probs
            float ent = 0.f;
            #pragma unroll
            for (int a = 0; a < A; ++a) {
                float lp = logit_s[a] - logZ;
                ent -= __expf(lp) * lp;
            }
            out[T + t] = ent;                         // entropies
        }
    }
}

extern "C" void kernel_launch(void* const* d_in, const int* in_sizes, int n_in,
                              void* d_out, int out_size, void* d_ws, size_t ws_size,
                              hipStream_t stream) {
    const int*   old_actions = (const int*)  d_in[0];
    const float* init_input  = (const float*)d_in[1];
    const float* W_ih_a      = (const float*)d_in[2];
    const float* W_hh_a      = (const float*)d_in[3];
    const float* b_ih_a      = (const float*)d_in[4];
    const float* b_hh_a      = (const float*)d_in[5];
    const float* heads_W     = (const float*)d_in[6];
    const float* heads_b     = (const float*)d_in[7];
    const float* W_ih_c      = (const float*)d_in[8];
    const float* W_hh_c      = (const float*)d_in[9];
    const float* b_ih_c      = (const float*)d_in[10];
    const float* b_hh_c      = (const float*)d_in[11];
    const float* critic_W    = (const float*)d_in[12];
    const float* critic_b    = (const float*)d_in[13];
    const float* embed       = (const float*)d_in[14];
    float* out = (float*)d_out;

    ppo_ctrl_kernel<<<dim3(2), dim3(512), 0, stream>>>(
        old_actions, init_input,
        W_ih_a, W_hh_a, b_ih_a, b_hh_a,
        heads_W, heads_b,
        W_ih_c, W_hh_c, b_ih_c, b_hh_c,
        critic_W, critic_b, embed, out);
}